// Round 1
// baseline (37.340 us; speedup 1.0000x reference)
//
#include <hip/hip_runtime.h>

// 14-qubit statevector sim, batch 256.
// One workgroup per batch element; full state (16384 x complex64 = 128 KiB) in LDS.
//
// Math collapse vs reference:
//  - initial RY(pi*latent[b,q]) + layer-0 RY/RZ/RY on qubit q fuse to one 2x2;
//    applied to |0..0> the state is a tensor product => built from two 128-entry
//    product tables, no gate passes for layer 0.
//  - CNOT chain (MSB-indexed controls in the reference) composes to the Gray map
//    new[l] = old[l ^ (l>>1)]. First chain is folded into layer-1 gate addressing
//    (logical l lives at physical l^(l>>1)); second chain folds into the output
//    read: out[l] = |st[l ^ (l>>2)]|^2.
//  - layer-1 RY(a),RZ(t),RY(c) per qubit fuse into one complex 2x2 (batch-invariant).

constexpr int NQ  = 14;
constexpr int DIM = 1 << NQ;   // 16384
constexpr int NT  = 1024;

__device__ __forceinline__ float2 cmul(float2 a, float2 b) {
    return make_float2(a.x * b.x - a.y * b.y, a.x * b.y + a.y * b.x);
}

__global__ __launch_bounds__(NT, 1)
void qsim_kernel(const float* __restrict__ latent,
                 const float* __restrict__ weights,
                 float* __restrict__ out)
{
    extern __shared__ float2 lds[];
    float2* st  = lds;             // [DIM]   state (physical layout = pre-first-chain order)
    float2* vq  = lds + DIM;       // [NQ][2] layer-0 fused column vectors
    float2* m1  = vq + 2 * NQ;     // [NQ][4] layer-1 fused matrices (M00,M01,M10,M11)
    float2* plo = m1 + 4 * NQ;     // [128]   product over bits 0..6
    float2* phi = plo + 128;       // [128]   product over bits 7..13

    const int b   = blockIdx.x;
    const int tid = threadIdx.x;

    // ---- per-qubit fused gate parameters ----
    if (tid < NQ) {
        const int q = tid;
        // layer 0 fused with initial RY: only column 0 needed (input |0>)
        const float a = weights[3 * q] + 3.14159265358979323846f * latent[b * NQ + q];
        const float t = weights[3 * q + 1];
        const float c = weights[3 * q + 2];
        const float ct = cosf(0.5f * t),      stt = sinf(0.5f * t);
        const float cp = cosf(0.5f * (a + c)), sp = sinf(0.5f * (a + c));
        const float cm = cosf(0.5f * (a - c)), sm = sinf(0.5f * (a - c));
        vq[2 * q + 0] = make_float2(ct * cp, -stt * cm);   // <0|M|0>
        vq[2 * q + 1] = make_float2(ct * sp,  stt * sm);   // <1|M|0>
    } else if (tid >= 64 && tid < 64 + NQ) {
        const int q = tid - 64;
        const float a = weights[3 * NQ + 3 * q];
        const float t = weights[3 * NQ + 3 * q + 1];
        const float c = weights[3 * NQ + 3 * q + 2];
        const float ct = cosf(0.5f * t),      stt = sinf(0.5f * t);
        const float cp = cosf(0.5f * (a + c)), sp = sinf(0.5f * (a + c));
        const float cm = cosf(0.5f * (a - c)), sm = sinf(0.5f * (a - c));
        m1[4 * q + 0] = make_float2( ct * cp, -stt * cm);  // M00
        m1[4 * q + 1] = make_float2(-ct * sp,  stt * sm);  // M01
        m1[4 * q + 2] = make_float2( ct * sp,  stt * sm);  // M10
        m1[4 * q + 3] = make_float2( ct * cp,  stt * cm);  // M11
    }
    __syncthreads();

    // ---- product tables: plo[m] = prod_{j<7} vq[j][bit j], phi likewise bits 7..13 ----
    if (tid < 256) {
        const int half = tid >> 7;
        const int m    = tid & 127;
        const int qb   = half * 7;
        float2 p = make_float2(1.0f, 0.0f);
        #pragma unroll
        for (int j = 0; j < 7; ++j)
            p = cmul(p, vq[2 * (qb + j) + ((m >> j) & 1)]);
        (half ? phi : plo)[m] = p;
    }
    __syncthreads();

    // ---- state after layer-0 rotations (product state) ----
    #pragma unroll
    for (int k = 0; k < DIM / NT; ++k) {
        const int idx = tid + k * NT;
        st[idx] = cmul(plo[idx & 127], phi[idx >> 7]);
    }

    // ---- layer-1 gates; logical index l lives at physical g(l) = l ^ (l>>1) ----
    for (int q = 0; q < NQ; ++q) {
        __syncthreads();
        const float2 M00 = m1[4 * q + 0];
        const float2 M01 = m1[4 * q + 1];
        const float2 M10 = m1[4 * q + 2];
        const float2 M11 = m1[4 * q + 3];
        const int mask = (1 << q) - 1;
        #pragma unroll
        for (int j = 0; j < (DIM / 2) / NT; ++j) {     // 8 pairs/thread
            const int p  = tid + j * NT;
            const int l0 = ((p & ~mask) << 1) | (p & mask);
            const int l1 = l0 | (1 << q);
            const int p0 = l0 ^ (l0 >> 1);
            const int p1 = l1 ^ (l1 >> 1);
            const float2 s0 = st[p0];
            const float2 s1 = st[p1];
            const float2 a0 = cmul(M00, s0), b0 = cmul(M01, s1);
            const float2 a1 = cmul(M10, s0), b1 = cmul(M11, s1);
            st[p0] = make_float2(a0.x + b0.x, a0.y + b0.y);
            st[p1] = make_float2(a1.x + b1.x, a1.y + b1.y);
        }
    }
    __syncthreads();

    // ---- output: second chain folded in => out[l] = |st[l ^ (l>>2)]|^2 ----
    float4* out4 = reinterpret_cast<float4*>(out + (size_t)b * DIM);
    #pragma unroll
    for (int k = 0; k < DIM / (4 * NT); ++k) {
        const int v = tid + k * NT;        // float4 slot
        const int l = v * 4;
        float4 r;
        {
            const float2 a = st[(l + 0) ^ ((l + 0) >> 2)];
            r.x = a.x * a.x + a.y * a.y;
        }
        {
            const float2 a = st[(l + 1) ^ ((l + 1) >> 2)];
            r.y = a.x * a.x + a.y * a.y;
        }
        {
            const float2 a = st[(l + 2) ^ ((l + 2) >> 2)];
            r.z = a.x * a.x + a.y * a.y;
        }
        {
            const float2 a = st[(l + 3) ^ ((l + 3) >> 2)];
            r.w = a.x * a.x + a.y * a.y;
        }
        out4[v] = r;
    }
}

extern "C" void kernel_launch(void* const* d_in, const int* in_sizes, int n_in,
                              void* d_out, int out_size, void* d_ws, size_t ws_size,
                              hipStream_t stream) {
    const float* latent  = (const float*)d_in[0];   // [256][14]
    const float* weights = (const float*)d_in[1];   // [84]
    float* out = (float*)d_out;                     // [256][16384]

    const int B = in_sizes[0] / NQ;                 // 256
    const size_t lds_bytes = (size_t)(DIM + 2 * NQ + 4 * NQ + 256) * sizeof(float2);

    // >64 KiB dynamic LDS requires explicit opt-in (host-side, graph-capture safe).
    hipFuncSetAttribute((const void*)qsim_kernel,
                        hipFuncAttributeMaxDynamicSharedMemorySize,
                        (int)lds_bytes);

    qsim_kernel<<<B, NT, lds_bytes, stream>>>(latent, weights, out);
}

// Round 2
// 23.701 us; speedup vs baseline: 1.5754x; 1.5754x over previous
//
#include <hip/hip_runtime.h>

// 14-qubit statevector sim, batch 256. One workgroup (1024 thr) per batch element.
// State (16384 c64 = 128 KiB) lives in LDS in LOGICAL (post-first-CNOT-chain) order,
// slot-swizzled; threads hold 16 amplitudes in registers and apply 4 qubits per
// group entirely in-register. LDS is touched only at group handoffs (4 w + 4 r).
//
// Math collapse (validated round 0, absmax 3e-5):
//  - initial RY(pi*latent)+layer-0 RY/RZ/RY fuse per qubit; state after layer 0 is a
//    product state built from two 128-entry tables.
//  - CNOT chain == Gray map new[l] = old[l^(l>>1)]; first chain folded into init
//    (read P at l^(l>>1)), second chain folded into readout (|st[l^(l>>1)]|^2).
//  - layer-1 RY/RZ/RY fuse to one complex 2x2 per qubit (batch-invariant).

typedef float f32x2 __attribute__((ext_vector_type(2)));

constexpr int NQ  = 14;
constexpr int DIM = 1 << NQ;   // 16384
constexpr int NT  = 1024;

// LDS slot swizzle: XOR bits 4-7 into bits 0-3 -> all handoff patterns hit
// 16 distinct bank residues per 16-lane phase (conflict-free b64).
__device__ __forceinline__ int swz(int l) { return l ^ ((l >> 4) & 15); }

// In-register butterfly on qubit mapped to register-index bit BIT.
// M = {M00, M01, M10, M11} complex. Written as f32x2 ops for v_pk_fma_f32 codegen.
template<int BIT>
__device__ __forceinline__ void applyQ(f32x2* s, const f32x2* M) {
    const f32x2 M00 = M[0], M01 = M[1], M10 = M[2], M11 = M[3];
    #pragma unroll
    for (int h = 0; h < 8; ++h) {
        const int i0 = ((h & ~(BIT - 1)) << 1) | (h & (BIT - 1));
        const int i1 = i0 | BIT;
        const f32x2 s0 = s[i0], s1 = s[i1];
        const f32x2 r0 = {-s0.y, s0.x};          // i*s0
        const f32x2 r1 = {-s1.y, s1.x};          // i*s1
        s[i0] = s0 * M00.x + r0 * M00.y + s1 * M01.x + r1 * M01.y;
        s[i1] = s0 * M10.x + r0 * M10.y + s1 * M11.x + r1 * M11.y;
    }
}

__global__ __launch_bounds__(NT, 4)
void qsim_kernel(const float* __restrict__ latent,
                 const float* __restrict__ weights,
                 float* __restrict__ out)
{
    extern __shared__ f32x2 lds[];
    f32x2* st  = lds;              // [DIM]  state, swizzled slots
    f32x2* vq  = lds + DIM;        // [2*NQ] layer-0 fused column vectors
    f32x2* m1  = vq + 2 * NQ;      // [4*NQ] layer-1 fused matrices
    f32x2* plo = m1 + 4 * NQ;      // [128]  product, bits 0..6
    f32x2* phi = plo + 128;        // [128]  product, bits 7..13

    const int b   = blockIdx.x;
    const int tid = threadIdx.x;

    // ---- fused per-qubit gate parameters ----
    if (tid < NQ) {
        const int q = tid;
        const float a = weights[3 * q] + 3.14159265358979323846f * latent[b * NQ + q];
        const float t = weights[3 * q + 1];
        const float c = weights[3 * q + 2];
        const float ct = cosf(0.5f * t),       stt = sinf(0.5f * t);
        const float cp = cosf(0.5f * (a + c)), sp  = sinf(0.5f * (a + c));
        const float cm = cosf(0.5f * (a - c)), sm  = sinf(0.5f * (a - c));
        vq[2 * q + 0] = f32x2{ct * cp, -stt * cm};
        vq[2 * q + 1] = f32x2{ct * sp,  stt * sm};
    } else if (tid >= 64 && tid < 64 + NQ) {
        const int q = tid - 64;
        const float a = weights[3 * NQ + 3 * q];
        const float t = weights[3 * NQ + 3 * q + 1];
        const float c = weights[3 * NQ + 3 * q + 2];
        const float ct = cosf(0.5f * t),       stt = sinf(0.5f * t);
        const float cp = cosf(0.5f * (a + c)), sp  = sinf(0.5f * (a + c));
        const float cm = cosf(0.5f * (a - c)), sm  = sinf(0.5f * (a - c));
        m1[4 * q + 0] = f32x2{ ct * cp, -stt * cm};
        m1[4 * q + 1] = f32x2{-ct * sp,  stt * sm};
        m1[4 * q + 2] = f32x2{ ct * sp,  stt * sm};
        m1[4 * q + 3] = f32x2{ ct * cp,  stt * cm};
    }
    __syncthreads();

    // ---- product tables ----
    if (tid < 256) {
        const int half = tid >> 7;
        const int m    = tid & 127;
        const int qb   = half * 7;
        f32x2 p = {1.0f, 0.0f};
        #pragma unroll
        for (int j = 0; j < 7; ++j) {
            const f32x2 v = vq[2 * (qb + j) + ((m >> j) & 1)];
            p = f32x2{p.x * v.x - p.y * v.y, p.x * v.y + p.y * v.x};
        }
        (half ? phi : plo)[m] = p;
    }
    __syncthreads();

    f32x2 s[16];

    // ---- G0: qubits 0-3.  l = (tid<<4)|r ; init folds Gray map ----
    #pragma unroll
    for (int r = 0; r < 16; ++r) {
        const int l = (tid << 4) | r;
        const int m = l ^ (l >> 1);
        const f32x2 a = plo[m & 127], c = phi[m >> 7];
        s[r] = f32x2{a.x * c.x - a.y * c.y, a.x * c.y + a.y * c.x};
    }
    applyQ<1>(s, m1 + 0);  applyQ<2>(s, m1 + 4);
    applyQ<4>(s, m1 + 8);  applyQ<8>(s, m1 + 12);
    #pragma unroll
    for (int r = 0; r < 16; ++r) st[swz((tid << 4) | r)] = s[r];
    __syncthreads();

    // ---- G1: qubits 4-7.  l = (tid>>4)<<8 | r<<4 | (tid&15) ----
    #pragma unroll
    for (int r = 0; r < 16; ++r)
        s[r] = st[swz(((tid >> 4) << 8) | (r << 4) | (tid & 15))];
    applyQ<1>(s, m1 + 16); applyQ<2>(s, m1 + 20);
    applyQ<4>(s, m1 + 24); applyQ<8>(s, m1 + 28);
    #pragma unroll
    for (int r = 0; r < 16; ++r)
        st[swz(((tid >> 4) << 8) | (r << 4) | (tid & 15))] = s[r];
    __syncthreads();

    // ---- G2: qubits 8-11. l = (tid>>8)<<12 | r<<8 | (tid&255) ----
    #pragma unroll
    for (int r = 0; r < 16; ++r)
        s[r] = st[swz(((tid >> 8) << 12) | (r << 8) | (tid & 255))];
    applyQ<1>(s, m1 + 32); applyQ<2>(s, m1 + 36);
    applyQ<4>(s, m1 + 40); applyQ<8>(s, m1 + 44);
    #pragma unroll
    for (int r = 0; r < 16; ++r)
        st[swz(((tid >> 8) << 12) | (r << 8) | (tid & 255))] = s[r];
    __syncthreads();

    // ---- G3: qubits 12-13. l = (r>>2)<<12 | tid<<2 | (r&3) ----
    #pragma unroll
    for (int r = 0; r < 16; ++r)
        s[r] = st[swz(((r >> 2) << 12) | (tid << 2) | (r & 3))];
    applyQ<4>(s, m1 + 48); applyQ<8>(s, m1 + 52);   // reg bits 2,3 = qubits 12,13
    #pragma unroll
    for (int r = 0; r < 16; ++r)
        st[swz(((r >> 2) << 12) | (tid << 2) | (r & 3))] = s[r];
    __syncthreads();

    // ---- readout: out[l] = |st[l ^ (l>>1)]|^2, coalesced float4 stores ----
    float4* out4 = reinterpret_cast<float4*>(out + (size_t)b * DIM);
    #pragma unroll
    for (int k = 0; k < 4; ++k) {
        const int v = tid + k * NT;
        const int l = v << 2;
        float4 o;
        { const int m = (l + 0) ^ ((l + 0) >> 1); const f32x2 a = st[swz(m)]; o.x = a.x * a.x + a.y * a.y; }
        { const int m = (l + 1) ^ ((l + 1) >> 1); const f32x2 a = st[swz(m)]; o.y = a.x * a.x + a.y * a.y; }
        { const int m = (l + 2) ^ ((l + 2) >> 1); const f32x2 a = st[swz(m)]; o.z = a.x * a.x + a.y * a.y; }
        { const int m = (l + 3) ^ ((l + 3) >> 1); const f32x2 a = st[swz(m)]; o.w = a.x * a.x + a.y * a.y; }
        out4[v] = o;
    }
}

extern "C" void kernel_launch(void* const* d_in, const int* in_sizes, int n_in,
                              void* d_out, int out_size, void* d_ws, size_t ws_size,
                              hipStream_t stream) {
    const float* latent  = (const float*)d_in[0];   // [256][14]
    const float* weights = (const float*)d_in[1];   // [84]
    float* out = (float*)d_out;                     // [256][16384]

    const int B = in_sizes[0] / NQ;                 // 256
    const size_t lds_bytes = (size_t)(DIM + 2 * NQ + 4 * NQ + 256) * sizeof(f32x2);

    hipFuncSetAttribute((const void*)qsim_kernel,
                        hipFuncAttributeMaxDynamicSharedMemorySize,
                        (int)lds_bytes);

    qsim_kernel<<<B, NT, lds_bytes, stream>>>(latent, weights, out);
}

// Round 3
// 12.977 us; speedup vs baseline: 2.8775x; 1.8264x over previous
//
#include <hip/hip_runtime.h>

// 14-qubit statevector sim, batch 256 — fully collapsed form.
//
// Validated folds (rounds 0-1, absmax 3e-5):
//   s0 = product state (fused initial-RY + layer-0 RY/RZ/RY per qubit),
//   CNOT chain == Gray map g(l) = l ^ (l>>1), layer-1 fuses to one 2x2 per qubit.
// New collapse (this round): substituting n = g(m') in s2 = G * C * s0 gives
//   m'_q = parity(n>>q); for q<7 that is parity(n_lo>>q) XOR parity(n_hi).
// Hence the FINAL STATE IS RANK-2 SEPARABLE:
//   s2[m_hi,m_lo] = d0[m_hi] c0[m_lo] + d1[m_hi] c1[m_lo]
// with c_p = (tensor_{q<7} M_q) x_p,  x_p[u] = plo[g7(u) ^ 64p]
//      d_p = (tensor_{q>=7} M_q) y_p, y_p[u] = (u&1)==p ? phi[g7(u)] : 0
// (g7(x) = x^(x>>1) on 7 bits; g7 linear over XOR, g7(127) = 64).
// Each c/d is one wave applying 7 butterfly levels via __shfl_xor.
// Readout (second chain folded): out[l] = |s2[g(l)]|^2
//   = e0[A] f0[j] + e1[A] f1[j] + ez[A].fz[j]   (4 real FMAs)
// with A = l>>7, j = (l&127) ^ (127 * (A&1)), tables stored in readout order.

typedef float f32x2 __attribute__((ext_vector_type(2)));

constexpr int NQ    = 14;
constexpr int DIM   = 1 << NQ;     // 16384
constexpr int NT    = 256;
constexpr int SPLIT = 4;           // blocks per batch element
constexpr int CHUNK = DIM / SPLIT; // 4096 outputs per block

__device__ __forceinline__ f32x2 cmul(f32x2 a, f32x2 b) {
    return f32x2{a.x * b.x - a.y * b.y, a.x * b.y + a.y * b.x};
}
__device__ __forceinline__ int g7(int x)  { return x ^ (x >> 1); }
__device__ __forceinline__ int g7i(int x) { x ^= x >> 1; x ^= x >> 2; x ^= x >> 4; return x; }

__global__ __launch_bounds__(NT)
void qsim_kernel(const float* __restrict__ latent,
                 const float* __restrict__ weights,
                 float* __restrict__ out)
{
    __shared__ f32x2 vq [2 * NQ];      // layer-0 fused columns
    __shared__ f32x2 m1 [4 * NQ];      // layer-1 fused 2x2 matrices
    __shared__ f32x2 plo[128], phi[128];
    __shared__ f32x2 cc0[128], cc1[128], dd0[128], dd1[128];
    __shared__ float4 fj[128];         // per-j  (|c0|^2, |c1|^2, zc.x, zc.y)
    __shared__ float4 eA[128];         // per-A  (|d0|^2, |d1|^2, 2 zd.x, -2 zd.y)

    const int b   = blockIdx.x >> 2;
    const int qtr = blockIdx.x & 3;
    const int tid = threadIdx.x;

    // ---- Phase A: fused per-qubit gate parameters ----
    if (tid < NQ) {
        const int q = tid;
        const float a = weights[3 * q] + 3.14159265358979323846f * latent[b * NQ + q];
        const float t = weights[3 * q + 1];
        const float c = weights[3 * q + 2];
        const float ct = cosf(0.5f * t),       stt = sinf(0.5f * t);
        const float cp = cosf(0.5f * (a + c)), sp  = sinf(0.5f * (a + c));
        const float cm = cosf(0.5f * (a - c)), sm  = sinf(0.5f * (a - c));
        vq[2 * q + 0] = f32x2{ct * cp, -stt * cm};
        vq[2 * q + 1] = f32x2{ct * sp,  stt * sm};
    } else if (tid >= 64 && tid < 64 + NQ) {
        const int q = tid - 64;
        const float a = weights[3 * NQ + 3 * q];
        const float t = weights[3 * NQ + 3 * q + 1];
        const float c = weights[3 * NQ + 3 * q + 2];
        const float ct = cosf(0.5f * t),       stt = sinf(0.5f * t);
        const float cp = cosf(0.5f * (a + c)), sp  = sinf(0.5f * (a + c));
        const float cm = cosf(0.5f * (a - c)), sm  = sinf(0.5f * (a - c));
        m1[4 * q + 0] = f32x2{ ct * cp, -stt * cm};
        m1[4 * q + 1] = f32x2{-ct * sp,  stt * sm};
        m1[4 * q + 2] = f32x2{ ct * sp,  stt * sm};
        m1[4 * q + 3] = f32x2{ ct * cp,  stt * cm};
    }
    __syncthreads();

    // ---- Phase B: product tables (128 low / 128 high) ----
    {
        const int half = tid >> 7;       // 0: plo, 1: phi
        const int m    = tid & 127;
        const int qb   = half * 7;
        f32x2 p = {1.0f, 0.0f};
        #pragma unroll
        for (int j = 0; j < 7; ++j)
            p = cmul(p, vq[2 * (qb + j) + ((m >> j) & 1)]);
        (half ? phi : plo)[m] = p;
    }
    __syncthreads();

    // ---- Phase C: four 128-vector butterfly pipelines, one per wave ----
    {
        const int w    = tid >> 6;       // 0:c0 1:c1 2:d0 3:d1
        const int lane = tid & 63;
        const int u0 = 2 * lane, u1 = 2 * lane + 1;

        f32x2 r0, r1;
        if (w == 0)      { r0 = plo[g7(u0)];       r1 = plo[g7(u1)];       }
        else if (w == 1) { r0 = plo[g7(u0) ^ 64];  r1 = plo[g7(u1) ^ 64];  }
        else if (w == 2) { r0 = phi[g7(u0)];       r1 = f32x2{0.f, 0.f};   }
        else             { r0 = f32x2{0.f, 0.f};   r1 = phi[g7(u1)];       }

        const int mbase = (w >> 1) * 7;  // qubits 0-6 or 7-13

        // level 0: bit 0 of u lives in-register
        {
            const f32x2 M00 = m1[4 * mbase + 0], M01 = m1[4 * mbase + 1];
            const f32x2 M10 = m1[4 * mbase + 2], M11 = m1[4 * mbase + 3];
            const f32x2 n0 = cmul(M00, r0) + cmul(M01, r1);
            const f32x2 n1 = cmul(M10, r0) + cmul(M11, r1);
            r0 = n0; r1 = n1;
        }
        // levels 1..6: bit k of u == bit k-1 of lane -> shfl_xor partner
        #pragma unroll
        for (int k = 1; k < 7; ++k) {
            const int q = mbase + k;
            const f32x2 M00 = m1[4 * q + 0], M01 = m1[4 * q + 1];
            const f32x2 M10 = m1[4 * q + 2], M11 = m1[4 * q + 3];
            const int msk = 1 << (k - 1);
            const int bit = (lane >> (k - 1)) & 1;
            f32x2 p0, p1;
            p0.x = __shfl_xor(r0.x, msk, 64); p0.y = __shfl_xor(r0.y, msk, 64);
            p1.x = __shfl_xor(r1.x, msk, 64); p1.y = __shfl_xor(r1.y, msk, 64);
            const f32x2 lo0 = bit ? p0 : r0, hi0 = bit ? r0 : p0;
            const f32x2 lo1 = bit ? p1 : r1, hi1 = bit ? r1 : p1;
            const f32x2 Ma  = bit ? M10 : M00;
            const f32x2 Mb  = bit ? M11 : M01;
            r0 = cmul(Ma, lo0) + cmul(Mb, hi0);
            r1 = cmul(Ma, lo1) + cmul(Mb, hi1);
        }
        // store in readout order: cc_p[j] = c_p[g7(j)]  ->  index g7i(m)
        const int j0 = g7i(u0), j1 = g7i(u1);
        if (w == 0)      { cc0[j0] = r0; cc0[j1] = r1; }
        else if (w == 1) { cc1[j0] = r0; cc1[j1] = r1; }
        else if (w == 2) { dd0[j0] = r0; dd0[j1] = r1; }
        else             { dd1[j0] = r0; dd1[j1] = r1; }
    }
    __syncthreads();

    // ---- Phase D: pack real readout tables ----
    if (tid < 128) {
        const int j = tid;
        const f32x2 c0 = cc0[j], c1 = cc1[j];
        fj[j] = make_float4(c0.x * c0.x + c0.y * c0.y,
                            c1.x * c1.x + c1.y * c1.y,
                            c0.x * c1.x + c0.y * c1.y,     // zc.x
                            c0.y * c1.x - c0.x * c1.y);    // zc.y
    } else {
        const int A = tid - 128;
        const f32x2 d0 = dd0[A], d1 = dd1[A];
        eA[A] = make_float4(d0.x * d0.x + d0.y * d0.y,
                            d1.x * d1.x + d1.y * d1.y,
                            2.0f * (d0.x * d1.x + d0.y * d1.y),    //  2 zd.x
                           -2.0f * (d0.y * d1.x - d0.x * d1.y));   // -2 zd.y
    }
    __syncthreads();

    // ---- Phase E: readout. out[l] = e(A) . f(j), coalesced dword stores ----
    float* outb = out + (size_t)b * DIM + qtr * CHUNK;
    #pragma unroll
    for (int k = 0; k < CHUNK / NT; ++k) {
        const int ll = tid + k * NT;               // local output index
        const int l  = qtr * CHUNK + ll;           // global output index
        const int A  = l >> 7;                     // uniform per wave
        const int j  = (l & 127) ^ ((A & 1) ? 127 : 0);
        const float4 e = eA[A];
        const float4 f = fj[j];
        outb[ll] = e.x * f.x + e.y * f.y + e.z * f.z + e.w * f.w;
    }
}

extern "C" void kernel_launch(void* const* d_in, const int* in_sizes, int n_in,
                              void* d_out, int out_size, void* d_ws, size_t ws_size,
                              hipStream_t stream) {
    const float* latent  = (const float*)d_in[0];   // [256][14]
    const float* weights = (const float*)d_in[1];   // [84]
    float* out = (float*)d_out;                     // [256][16384]

    const int B = in_sizes[0] / NQ;                 // 256
    qsim_kernel<<<B * SPLIT, NT, 0, stream>>>(latent, weights, out);
}